// Round 8
// baseline (212.705 us; speedup 1.0000x reference)
//
#include <hip/hip_runtime.h>
#include <hip/hip_bf16.h>

// Problem constants
#define BB 2
#define TT 2048
#define DD 512
#define HH 8
#define DH 64
#define INNER 512
#define MAXLAG 5

typedef __attribute__((ext_vector_type(8))) short short8;
typedef __attribute__((ext_vector_type(4))) float floatx4;
typedef unsigned short ushort_t;

__device__ inline unsigned short f2bf(float f) {
    unsigned u = __float_as_uint(f);
    unsigned r = (u + 0x7FFFu + ((u >> 16) & 1u)) >> 16;
    return (unsigned short)r;
}
__device__ inline float bf2f(unsigned short u) {
    return __uint_as_float(((unsigned)u) << 16);
}

// ---------------------------------------------------------------------------
// Fused convert: blocks [0,1024): x -> bf16; blocks [1024,2048): weight
// transpose+convert via 32x32 LDS tile (Wt[n][k] = bf16(W[k][n])).
// ---------------------------------------------------------------------------
__global__ __launch_bounds__(256)
void cvt_kernel(const float* __restrict__ x,
                const float* __restrict__ wq, const float* __restrict__ wk,
                const float* __restrict__ wv, const float* __restrict__ wo,
                ushort_t* __restrict__ xb,
                ushort_t* __restrict__ wqt, ushort_t* __restrict__ wkt,
                ushort_t* __restrict__ wvt, ushort_t* __restrict__ wot)
{
    __shared__ float T[32][33];
    const int bid = blockIdx.x;
    if (bid < 1024) {
        int off = (bid * 256 + threadIdx.x) * 8;
        float4 a = *(const float4*)&x[off];
        float4 b = *(const float4*)&x[off + 4];
        ushort_t t[8];
        t[0] = f2bf(a.x); t[1] = f2bf(a.y); t[2] = f2bf(a.z); t[3] = f2bf(a.w);
        t[4] = f2bf(b.x); t[5] = f2bf(b.y); t[6] = f2bf(b.z); t[7] = f2bf(b.w);
        *(uint4*)&xb[off] = *(const uint4*)t;
        return;
    }
    const int r = bid - 1024;
    const int z = r >> 8;
    const int tile = r & 255;
    const float* s = (z == 0) ? wq : (z == 1) ? wk : (z == 2) ? wv : wo;
    ushort_t*    d = (z == 0) ? wqt : (z == 1) ? wkt : (z == 2) ? wvt : wot;
    const int k0 = (tile & 15) * 32;
    const int n0 = (tile >> 4) * 32;
    {
        const int kk = threadIdx.x >> 3;
        const int n4 = (threadIdx.x & 7) * 4;
        float4 v = *(const float4*)&s[(size_t)(k0 + kk) * 512 + n0 + n4];
        T[kk][n4 + 0] = v.x; T[kk][n4 + 1] = v.y;
        T[kk][n4 + 2] = v.z; T[kk][n4 + 3] = v.w;
    }
    __syncthreads();
    {
        const int nn = threadIdx.x >> 3;
        const int k4 = (threadIdx.x & 7) * 4;
        ushort4 o;
        o.x = f2bf(T[k4 + 0][nn]); o.y = f2bf(T[k4 + 1][nn]);
        o.z = f2bf(T[k4 + 2][nn]); o.w = f2bf(T[k4 + 3][nn]);
        *(ushort4*)&d[(size_t)(n0 + nn) * 512 + k0 + k4] = o;
    }
}

// ---------------------------------------------------------------------------
// bf16 MFMA GEMM, 64x64x32 tiles (unchanged from R7, passing).
// vtrans: blockIdx.z==2 writes V TRANSPOSED: O2[((b*8+h)*64+d)*2048 + t].
// ---------------------------------------------------------------------------
#define GM 64
#define GN 64
#define GK 32

template <typename OutT>
__global__ __launch_bounds__(256)
void gemm64(const ushort_t* __restrict__ A,
            const ushort_t* __restrict__ B0, const ushort_t* __restrict__ B1,
            const ushort_t* __restrict__ B2,
            OutT* __restrict__ O0, OutT* __restrict__ O1, OutT* __restrict__ O2,
            const float* __restrict__ bias, int M, int N, int K, int vtrans)
{
    const ushort_t* Bw = (blockIdx.z == 0) ? B0 : ((blockIdx.z == 1) ? B1 : B2);
    OutT*           O  = (blockIdx.z == 0) ? O0 : ((blockIdx.z == 1) ? O1 : O2);
    const int dotrans = vtrans && (blockIdx.z == 2);

    __shared__ ushort_t As[GM * GK];
    __shared__ ushort_t Bs[GN * GK];

    const int tid  = threadIdx.x;
    const int wave = tid >> 6;
    const int lane = tid & 63;
    const int quad = lane >> 4;
    const int l15  = lane & 15;
    const int wr   = wave >> 1;
    const int wc   = wave & 1;
    const int bm   = blockIdx.y * GM;
    const int bn   = blockIdx.x * GN;

    const ushort_t* ap = &A[(size_t)(bm + (tid >> 2)) * K + (tid & 3) * 8];
    const ushort_t* bp = &Bw[(size_t)(bn + (tid >> 2)) * K + (tid & 3) * 8];

    floatx4 acc[2][2];
#pragma unroll
    for (int i = 0; i < 2; ++i)
#pragma unroll
        for (int j = 0; j < 2; ++j) acc[i][j] = (floatx4){0.f, 0.f, 0.f, 0.f};

    uint4 pa = *(const uint4*)ap;
    uint4 pb = *(const uint4*)bp;

    for (int k0 = 0; k0 < K; k0 += GK) {
        __syncthreads();
        *(uint4*)&As[tid * 8] = pa;
        *(uint4*)&Bs[tid * 8] = pb;
        if (k0 + GK < K) {
            pa = *(const uint4*)(ap + k0 + GK);
            pb = *(const uint4*)(bp + k0 + GK);
        }
        __syncthreads();

        short8 af[2], bf[2];
#pragma unroll
        for (int mt = 0; mt < 2; ++mt)
            af[mt] = *(const short8*)&As[(((wr * 32 + mt * 16 + l15) << 2) + quad) * 8];
#pragma unroll
        for (int nt = 0; nt < 2; ++nt)
            bf[nt] = *(const short8*)&Bs[(((wc * 32 + nt * 16 + l15) << 2) + quad) * 8];
#pragma unroll
        for (int mt = 0; mt < 2; ++mt)
#pragma unroll
            for (int nt = 0; nt < 2; ++nt)
                acc[mt][nt] = __builtin_amdgcn_mfma_f32_16x16x32_bf16(
                    af[mt], bf[nt], acc[mt][nt], 0, 0, 0);
    }

    if (dotrans) {
#pragma unroll
        for (int mt = 0; mt < 2; ++mt) {
            const int m0 = bm + wr * 32 + mt * 16 + quad * 4;
            const int b  = m0 >> 11;
            const int t0 = m0 & 2047;
#pragma unroll
            for (int nt = 0; nt < 2; ++nt) {
                const int n = bn + wc * 32 + nt * 16 + l15;
                const int h = n >> 6, dd = n & 63;
                ushort4 o;
                o.x = f2bf(acc[mt][nt][0]); o.y = f2bf(acc[mt][nt][1]);
                o.z = f2bf(acc[mt][nt][2]); o.w = f2bf(acc[mt][nt][3]);
                *(ushort4*)&((ushort_t*)O)[((size_t)((b * 8 + h) * 64 + dd)) * 2048 + t0] = o;
            }
        }
        return;
    }

    float bv[2] = {0.f, 0.f};
    if (bias) {
#pragma unroll
        for (int nt = 0; nt < 2; ++nt)
            bv[nt] = bias[bn + wc * 32 + nt * 16 + l15];
    }
#pragma unroll
    for (int mt = 0; mt < 2; ++mt) {
#pragma unroll
        for (int nt = 0; nt < 2; ++nt) {
            const int n = bn + wc * 32 + nt * 16 + l15;
#pragma unroll
            for (int reg = 0; reg < 4; ++reg) {
                const int m = bm + wr * 32 + mt * 16 + quad * 4 + reg;
                float v = acc[mt][nt][reg] + bv[nt];
                if constexpr (sizeof(OutT) == 2)
                    O[(size_t)m * N + n] = (OutT)f2bf(v);
                else
                    O[(size_t)m * N + n] = (OutT)v;
            }
        }
    }
}

// ---------------------------------------------------------------------------
// MFMA flash attention v4: NO K/V LDS staging, NO barriers. Each wave loads
// K/V^T MFMA fragments directly from global (LLC-resident; frag lanes cover
// aligned 128B lines). K-frags register-prefetched one iter ahead; V-frags
// issued at iter top, consumed after softmax. Pl (P C->A transform) stays
// in wave-private LDS. 2-way K-split + fixed-max softmax as R7.
// ---------------------------------------------------------------------------
#define PAD 72
#define MFIX 10.0f

__global__ __launch_bounds__(256)
void attn_mfma(const ushort_t* __restrict__ Qg,
               const ushort_t* __restrict__ Kg,
               const ushort_t* __restrict__ Vtg,
               const float* __restrict__ lagw,
               ushort_t* __restrict__ Opart,
               float* __restrict__ Lpart)
{
    __shared__ ushort_t Pl[4][16][PAD];

    const int tid  = threadIdx.x;
    const int wave = tid >> 6;
    const int lane = tid & 63;
    const int quad = lane >> 4;
    const int l15  = lane & 15;

    const int bh = blockIdx.y;
    const int b  = bh >> 3;
    const int h  = bh & 7;
    const int c  = blockIdx.x;         // heavy qt first
    const int qt = 31 - (c >> 1);
    const int sp = c & 1;
    const int i0 = qt * 64;
    const int h1 = (qt + 1) >> 1;
    const int lo = sp ? h1 : 0;
    const int hi = sp ? (qt + 1) : h1;

    float lagb[MAXLAG + 1];
    {
        float mx = -1e30f;
#pragma unroll
        for (int l = 0; l <= MAXLAG; ++l) {
            lagb[l] = lagw[h * (MAXLAG + 1) + l];
            mx = fmaxf(mx, lagb[l]);
        }
        float s = 0.f;
#pragma unroll
        for (int l = 0; l <= MAXLAG; ++l) { lagb[l] = __expf(lagb[l] - mx); s += lagb[l]; }
        float inv = 1.f / s;
#pragma unroll
        for (int l = 0; l <= MAXLAG; ++l) lagb[l] = lagb[l] * inv - MFIX;
    }
    const float c1  = 0.125f;
    const float c2f = lagb[MAXLAG];

    short8 qf0, qf1;
    {
        const ushort_t* qbase =
            Qg + ((size_t)(b * TT + i0 + wave * 16 + l15)) * INNER + h * DH;
        qf0 = *(const short8*)(qbase + quad * 8);
        qf1 = *(const short8*)(qbase + 32 + quad * 8);
    }

    floatx4 oacc[4];
    float lsum[4] = {0.f, 0.f, 0.f, 0.f};
#pragma unroll
    for (int cb = 0; cb < 4; ++cb) oacc[cb] = (floatx4){0.f, 0.f, 0.f, 0.f};

    const int ibase = i0 + wave * 16 + quad * 4;

    // direct-global fragment bases (per-lane offsets are loop-invariant)
    const ushort_t* Kb = Kg + ((size_t)b * TT) * INNER + h * DH;   // + j*512 + d
    const ushort_t* Vb = Vtg + ((size_t)bh * 64) * TT;             // + d*2048 + j

    // per-lane, per-cb element offsets
    size_t koff[4], voff[4];
#pragma unroll
    for (int cb = 0; cb < 4; ++cb) {
        koff[cb] = (size_t)(cb * 16 + l15) * INNER + quad * 8;  // + j0*512
        voff[cb] = (size_t)(cb * 16 + l15) * TT + quad * 8;     // + j0
    }

    short8 ka0[4], ka1[4];
    if (lo < hi) {
        const size_t j0e = (size_t)(lo * 64) * INNER;
#pragma unroll
        for (int cb = 0; cb < 4; ++cb) {
            ka0[cb] = *(const short8*)(Kb + j0e + koff[cb]);
            ka1[cb] = *(const short8*)(Kb + j0e + koff[cb] + 32);
        }
    }

    for (int kt = lo; kt < hi; ++kt) {
        const int j0 = kt * 64;

        // V fragments for this iter (consumed after softmax)
        short8 vv0[4], vv1[4];
#pragma unroll
        for (int cb = 0; cb < 4; ++cb) {
            vv0[cb] = *(const short8*)(Vb + voff[cb] + j0);
            vv1[cb] = *(const short8*)(Vb + voff[cb] + j0 + 32);
        }
        // K prefetch for next iter
        short8 kn0[4], kn1[4];
        if (kt + 1 < hi) {
            const size_t jn = (size_t)(j0 + 64) * INNER;
#pragma unroll
            for (int cb = 0; cb < 4; ++cb) {
                kn0[cb] = *(const short8*)(Kb + jn + koff[cb]);
                kn1[cb] = *(const short8*)(Kb + jn + koff[cb] + 32);
            }
        }

        // S = Q @ K^T
        floatx4 sacc[4];
#pragma unroll
        for (int cb = 0; cb < 4; ++cb) {
            floatx4 z = (floatx4){0.f, 0.f, 0.f, 0.f};
            z = __builtin_amdgcn_mfma_f32_16x16x32_bf16(qf0, ka0[cb], z, 0, 0, 0);
            z = __builtin_amdgcn_mfma_f32_16x16x32_bf16(qf1, ka1[cb], z, 0, 0, 0);
            sacc[cb] = z;
        }

        float p[4][4];
        if (i0 + wave * 16 - (j0 + 63) >= MAXLAG) {
#pragma unroll
            for (int cb = 0; cb < 4; ++cb)
#pragma unroll
                for (int reg = 0; reg < 4; ++reg)
                    p[cb][reg] = __expf(fmaf(sacc[cb][reg], c1, c2f));
        } else {
#pragma unroll
            for (int cb = 0; cb < 4; ++cb) {
                const int j = j0 + cb * 16 + l15;
#pragma unroll
                for (int reg = 0; reg < 4; ++reg) {
                    const int lag = (ibase + reg) - j;
                    float bias = (lag <= 0) ? lagb[0]
                               : (lag == 1) ? lagb[1]
                               : (lag == 2) ? lagb[2]
                               : (lag == 3) ? lagb[3]
                               : (lag == 4) ? lagb[4] : lagb[5];
                    float e = __expf(fmaf(sacc[cb][reg], c1, bias));
                    p[cb][reg] = (lag < 0) ? 0.f : e;
                }
            }
        }
#pragma unroll
        for (int cb = 0; cb < 4; ++cb)
#pragma unroll
            for (int reg = 0; reg < 4; ++reg)
                lsum[reg] += p[cb][reg];

        // P: C-layout -> LDS -> A-layout (wave-private, no barrier)
#pragma unroll
        for (int cb = 0; cb < 4; ++cb)
#pragma unroll
            for (int reg = 0; reg < 4; ++reg)
                Pl[wave][quad * 4 + reg][cb * 16 + l15] = f2bf(p[cb][reg]);

        short8 pf0 = *(const short8*)&Pl[wave][l15][quad * 8];
        short8 pf1 = *(const short8*)&Pl[wave][l15][32 + quad * 8];

        // O += P @ V
#pragma unroll
        for (int cb = 0; cb < 4; ++cb) {
            oacc[cb] = __builtin_amdgcn_mfma_f32_16x16x32_bf16(pf0, vv0[cb], oacc[cb], 0, 0, 0);
            oacc[cb] = __builtin_amdgcn_mfma_f32_16x16x32_bf16(pf1, vv1[cb], oacc[cb], 0, 0, 0);
        }

#pragma unroll
        for (int cb = 0; cb < 4; ++cb) { ka0[cb] = kn0[cb]; ka1[cb] = kn1[cb]; }
    }

#pragma unroll
    for (int reg = 0; reg < 4; ++reg) {
        lsum[reg] += __shfl_xor(lsum[reg], 1);
        lsum[reg] += __shfl_xor(lsum[reg], 2);
        lsum[reg] += __shfl_xor(lsum[reg], 4);
        lsum[reg] += __shfl_xor(lsum[reg], 8);
    }

#pragma unroll
    for (int reg = 0; reg < 4; ++reg) {
        const int row = ibase + reg;
        const size_t obase = ((size_t)(sp * 16 + bh) * TT + row) * 64;
#pragma unroll
        for (int cb = 0; cb < 4; ++cb)
            Opart[obase + cb * 16 + l15] = f2bf(oacc[cb][reg]);
        if (l15 == 0)
            Lpart[(size_t)(sp * 16 + bh) * TT + row] = lsum[reg];
    }
}

// ---------------------------------------------------------------------------
// Combine the 2 K-split partials -> ao bf16 [b*T+i][h*64+d]
// ---------------------------------------------------------------------------
#define CMB_UNITS (16 * TT * 16)

__global__ __launch_bounds__(256)
void combine_kernel(const ushort_t* __restrict__ Opart,
                    const float* __restrict__ Lpart,
                    ushort_t* __restrict__ ao)
{
    int u = blockIdx.x * 256 + threadIdx.x;
    const int bh  = u >> 15;
    const int rem = u & 32767;
    const int i   = rem >> 4;
    const int d   = (rem & 15) * 4;
    const int b   = bh >> 3;
    const int h   = bh & 7;

    const size_t p0 = ((size_t)bh * TT + i) * 64 + d;
    const size_t p1 = ((size_t)(16 + bh) * TT + i) * 64 + d;
    ushort4 a0 = *(const ushort4*)&Opart[p0];
    ushort4 a1 = *(const ushort4*)&Opart[p1];
    const float l = Lpart[(size_t)bh * TT + i] + Lpart[(size_t)(16 + bh) * TT + i];
    const float inv = 1.f / l;

    ushort4 o;
    o.x = f2bf((bf2f(a0.x) + bf2f(a1.x)) * inv);
    o.y = f2bf((bf2f(a0.y) + bf2f(a1.y)) * inv);
    o.z = f2bf((bf2f(a0.z) + bf2f(a1.z)) * inv);
    o.w = f2bf((bf2f(a0.w) + bf2f(a1.w)) * inv);
    *(ushort4*)&ao[((size_t)(b * TT + i)) * INNER + h * DH + d] = o;
}

// ---------------------------------------------------------------------------
extern "C" void kernel_launch(void* const* d_in, const int* in_sizes, int n_in,
                              void* d_out, int out_size, void* d_ws, size_t ws_size,
                              hipStream_t stream)
{
    const float* x  = (const float*)d_in[0];
    const float* Wq = (const float*)d_in[1];
    const float* Wk = (const float*)d_in[2];
    const float* Wv = (const float*)d_in[3];
    const float* Wo = (const float*)d_in[4];
    const float* bo = (const float*)d_in[5];
    const float* lw = (const float*)d_in[6];
    float* out = (float*)d_out;

    const size_t SZ  = (size_t)BB * TT * INNER;  // 2M elements
    const size_t NWE = (size_t)DD * INNER;       // 256K per weight
    ushort_t* xb    = (ushort_t*)d_ws;
    ushort_t* wqt   = xb + SZ;
    ushort_t* wkt   = wqt + NWE;
    ushort_t* wvt   = wkt + NWE;
    ushort_t* wot   = wvt + NWE;
    ushort_t* q     = wot + NWE;
    ushort_t* k     = q + SZ;
    ushort_t* vt    = k + SZ;                    // V TRANSPOSED [bh][d][t]
    ushort_t* opart = vt + SZ;                   // 2 slots * 16*TT*64
    float*    lpart = (float*)(opart + 2 * SZ);
    ushort_t* ao    = xb;                        // alias: xb dead after QKV

    const int M = BB * TT;

    cvt_kernel<<<2048, 256, 0, stream>>>(x, Wq, Wk, Wv, Wo,
                                         xb, wqt, wkt, wvt, wot);

    dim3 gQKV(INNER / GN, M / GM, 3);
    gemm64<ushort_t><<<gQKV, 256, 0, stream>>>(
        xb, wqt, wkt, wvt, q, k, vt, nullptr, M, INNER, DD, 1);

    dim3 gATT(64, BB * HH);
    attn_mfma<<<gATT, 256, 0, stream>>>(q, k, vt, lw, opart, lpart);

    combine_kernel<<<CMB_UNITS / 256, 256, 0, stream>>>(opart, lpart, ao);

    dim3 gPRJ(DD / GN, M / GM, 1);
    gemm64<float><<<gPRJ, 256, 0, stream>>>(
        ao, wot, wot, wot, out, out, out, bo, M, DD, INNER, 0);
}